// Round 12
// baseline (692.684 us; speedup 1.0000x reference)
//
#include <hip/hip_runtime.h>
#include <hip/hip_bf16.h>
#include <math.h>

// Problem constants
#define Bn   16
#define Dn   64
#define Tn   3000
#define Nn   (Bn*Tn)          // 48000
#define NCB  8
#define Kn   1024
#define KTB  128              // codes per k-chunk (LDS staged)
#define NCHK (Kn/KTB)         // 8 chunks per codebook
#define NTB  64               // n per block
#define NBLK (Nn/NTB)         // 750 (exact) <= 768 = 256CU x 3 blocks
#define QMAX 768              // per-stage queue capacity (fallback path on overflow)

// LDS layout (bytes), total 53776 -> 3 blocks/CU (54613 cap)
#define SM_RH   0                      // bf16 [64n][64d] swizzled = 8192
#define SM_RL   8192                   // 8192
#define SM_EH   16384                  // bf16 [128k][64d] swizzled = 16384 (hi only)
#define SM_RF   32768                  // float [64d][64n] = 16384 (exact residual)
#define SM_SE   49152                  // float[128] chunk selds = 512
#define SM_SR   49664                  // float[64] = 256
#define SM_BEST 49920                  // u64[64] = 512
#define SM_QCNT 50432                  // int (+pad) = 16
#define SM_QUE  50448                  // u32[QMAX] = 3072
#define SM_BK   53520                  // int[64] = 256
#define SM_TOT  53776
// aliases on SM_QUE (queue dead then): srpart[256]f, red[256]f

// Workspace byte offsets
#define WS_EHI   12288000                      // u8[8cb][8chk][128k][128B] pre-swizzled bf16 hi
#define WS_SE    13336576                      // float[NCB*Kn]
#define WS_USED  13369344                      // float[NCB*Kn]
#define WS_LOSS  13402112                      // float[1]
#define WS_SEMAX 13402128                      // float[8]

// Output element offsets (fp32 elements)
#define OUT_QT_OFF  0
#define OUT_IDX_OFF 3072000
#define OUT_SC_OFF  3456000

typedef __attribute__((ext_vector_type(4))) float f32x4;
typedef __attribute__((ext_vector_type(8))) short s16x8;

__device__ __forceinline__ unsigned short f2bf(float x) {   // RNE bf16 bits
    unsigned int u = __float_as_uint(x);
    unsigned int r = (u + 0x7FFFu + ((u >> 16) & 1u)) >> 16;
    return (unsigned short)r;
}
__device__ __forceinline__ float bf2f(unsigned short h) {
    return __uint_as_float(((unsigned int)h) << 16);
}

// ---------- precompute ||e_k||^2 + per-codebook max ----------
__global__ void vq_se(const float* __restrict__ emb, float* __restrict__ se,
                      float* __restrict__ semax)
{
    int r = blockIdx.x * 256 + threadIdx.x;   // 0..8191
    if (r < NCB*Kn) {
        const float* p = emb + r*Dn;
        float a0=0.f, a1=0.f, a2=0.f, a3=0.f;
        #pragma unroll
        for (int d = 0; d < Dn; d += 4) {
            a0 = fmaf(p[d+0], p[d+0], a0);
            a1 = fmaf(p[d+1], p[d+1], a1);
            a2 = fmaf(p[d+2], p[d+2], a2);
            a3 = fmaf(p[d+3], p[d+3], a3);
        }
        float v = (a0+a1)+(a2+a3);
        se[r] = v;
        atomicMax((int*)&semax[r >> 10], __float_as_int(v));  // v >= 0: int order = float order
    }
}

// ---------- precompute bf16 hi split of all codebooks, pre-swizzled ----------
__global__ void vq_ebf(const float* __restrict__ emb, char* __restrict__ ehi)
{
    int idx = blockIdx.x * 256 + threadIdx.x;   // < 65536
    int r = idx >> 3;                            // cb*1024 + k
    int s = idx & 7;                             // dim slice
    const float* p = emb + (size_t)r*Dn + s*8;
    s16x8 hh;
    #pragma unroll
    for (int j = 0; j < 8; ++j) hh[j] = (short)f2bf(p[j]);
    int cb = r >> 10, kk = r & 1023, c = kk >> 7, kl = kk & 127;
    size_t off = (size_t)cb*131072 + (size_t)c*16384 + (size_t)kl*128 + ((s ^ (kl & 7)) << 4);
    *(s16x8*)(ehi + off) = hh;
}

// exact fp32 rescore: d2 = (sr - 2*dot) + sek  (identical chain since R8, verified)
__device__ __forceinline__
float vq_rescore(const float* rf, float sr, float sek,
                 const float* __restrict__ emb_cb, int n, int kg)
{
    const float4* ep = (const float4*)(emb_cb + (size_t)kg*Dn);
    float q0=0.f,q1=0.f,q2=0.f,q3=0.f;
    #pragma unroll 4
    for (int m = 0; m < 16; ++m) {
        float4 e4 = ep[m];
        q0 = fmaf(rf[(4*m+0)*64 + n], e4.x, q0);
        q1 = fmaf(rf[(4*m+1)*64 + n], e4.y, q1);
        q2 = fmaf(rf[(4*m+2)*64 + n], e4.z, q2);
        q3 = fmaf(rf[(4*m+3)*64 + n], e4.w, q3);
    }
    float dot = (q0+q1)+(q2+q3);
    return (sr - 2.0f*dot) + sek;
}

// ---------- mega kernel: all 8 stages fused, residual lives in LDS ----------
// grid NBLK, block 256 (4 waves). Wave w owns n-rows [w*16, w*16+16).
__global__ __launch_bounds__(256, 3)
void vq_mega(const float* __restrict__ x, const float* __restrict__ emb,
             const char* __restrict__ ehib, const float* __restrict__ se_g,
             const float* __restrict__ semax_g,
             float* __restrict__ out_qt, float* __restrict__ out_idx,
             float* __restrict__ used_g, float* __restrict__ loss_acc)
{
    __shared__ __align__(16) char smem[SM_TOT];
    float*  rf     = (float*)(smem + SM_RF);
    float*  selds  = (float*)(smem + SM_SE);
    float*  lds_sr = (float*)(smem + SM_SR);
    unsigned long long* best64 = (unsigned long long*)(smem + SM_BEST);
    int*    qcnt   = (int*)(smem + SM_QCNT);
    unsigned int* que = (unsigned int*)(smem + SM_QUE);
    float*  srpart = (float*)(smem + SM_QUE);    // alias (stage transitions only)
    int*    bkL    = (int*)(smem + SM_BK);

    const int tid = threadIdx.x;
    const int n0 = blockIdx.x * NTB;
    const int lane = tid & 63, w = tid >> 6;
    const int lrow = lane & 15, lhi = lane >> 4;
    const int nl = tid & 63;
    const int dg = tid >> 6;
    const float4* hsrc = (const float4*)ehib;

    // ---- prologue: stage R from x (fp32 rf + bf16 hi/lo swizzled) + sr partials ----
    {
        const int n = n0 + nl;
        const int b = n / Tn, t = n % Tn;
        const float* gp = x + b*(Dn*Tn) + t;
        float v[16];
        #pragma unroll
        for (int j = 0; j < 16; ++j) v[j] = gp[(dg*16 + j)*Tn];
        float a0=0.f,a1=0.f,a2=0.f,a3=0.f;
        #pragma unroll
        for (int j = 0; j < 16; j += 4) {
            a0 = fmaf(v[j+0], v[j+0], a0);
            a1 = fmaf(v[j+1], v[j+1], a1);
            a2 = fmaf(v[j+2], v[j+2], a2);
            a3 = fmaf(v[j+3], v[j+3], a3);
        }
        srpart[dg*64 + nl] = (a0+a1)+(a2+a3);
        unsigned short hi[16], lo[16];
        #pragma unroll
        for (int j = 0; j < 16; ++j) {
            rf[(dg*16 + j)*64 + nl] = v[j];
            hi[j] = f2bf(v[j]);
            lo[j] = f2bf(v[j] - bf2f(hi[j]));
        }
        s16x8 ph0, ph1, pl0, pl1;
        #pragma unroll
        for (int j = 0; j < 8; ++j) {
            ph0[j] = (short)hi[j];   ph1[j] = (short)hi[j+8];
            pl0[j] = (short)lo[j];   pl1[j] = (short)lo[j+8];
        }
        const int s0 = dg*2, s1 = dg*2 + 1, nx = nl & 7;
        *(s16x8*)(smem + SM_RH + nl*128 + ((s0 ^ nx) << 4)) = ph0;
        *(s16x8*)(smem + SM_RH + nl*128 + ((s1 ^ nx) << 4)) = ph1;
        *(s16x8*)(smem + SM_RL + nl*128 + ((s0 ^ nx) << 4)) = pl0;
        *(s16x8*)(smem + SM_RL + nl*128 + ((s1 ^ nx) << 4)) = pl1;
    }
    if (tid < 64) best64[tid] = ~0ULL;
    if (tid == 0) qcnt[0] = 0;
    __syncthreads();                               // srpart ready
    if (tid < 64)
        lds_sr[tid] = (srpart[tid] + srpart[64+tid]) + (srpart[128+tid] + srpart[192+tid]);
    // stage E(cb0, chunk0): 16 KB linear copy of pre-swizzled hi
    ((float4*)(smem + SM_EH))[tid]       = hsrc[tid];
    ((float4*)(smem + SM_EH))[tid+256]   = hsrc[tid+256];
    ((float4*)(smem + SM_EH))[tid+512]   = hsrc[tid+512];
    ((float4*)(smem + SM_EH))[tid+768]   = hsrc[tid+768];
    if (tid < KTB) selds[tid] = se_g[tid];

    float lsum = 0.f;
    const int nlocal = w*16 + lrow;

    // ================= stage loop =================
    for (int s = 0; s < NCB; ++s) {
        const float* emb_s = emb + (size_t)s*(Kn*Dn);
        const float semx = semax_g[s];
        float m_run = INFINITY;
        float band = 0.f;

        // ---- chunk loop (8 x 128 codes) ----
        for (int c = 0; c < NCHK; ++c) {
            __syncthreads();                       // E(c)/selds(c)/RH/RL/lds_sr ready
            if (c == 0)                            // per-n rigorous candidate band
                band = 0.0095f * sqrtf(semx * lds_sr[nlocal]) + 2e-4f;

            // prefetch next E chunk (or next codebook's chunk 0) into regs
            const bool pre = (c < NCHK-1) || (s < NCB-1);
            float4 h0, h1, h2, h3; float sepre = 0.f;
            if (pre) {
                size_t nb = (c < NCHK-1) ? ((size_t)s*8192 + (size_t)(c+1)*1024)
                                         : ((size_t)(s+1)*8192);
                h0 = hsrc[nb + tid];       h1 = hsrc[nb + 256 + tid];
                h2 = hsrc[nb + 512 + tid]; h3 = hsrc[nb + 768 + tid];
                if (tid < KTB)
                    sepre = se_g[(c < NCHK-1) ? (s*Kn + (c+1)*KTB + tid)
                                              : ((s+1)*Kn + tid)];
            }

            // MFMA: acc[i] = eh . (rh + rl)  (2-pass split, E-hi only)
            f32x4 acc[8];
            #pragma unroll
            for (int i = 0; i < 8; ++i) acc[i] = (f32x4){0.f,0.f,0.f,0.f};
            #pragma unroll
            for (int ks = 0; ks < 2; ++ks) {
                const int sdim = ks*4 + lhi;
                const int swz = ((sdim ^ (lrow & 7)) << 4);
                const size_t roff = (size_t)(w*16 + lrow)*128 + swz;
                const size_t eoff = (size_t)lrow*128 + swz;
                s16x8 bh = *(const s16x8*)(smem + SM_RH + roff);
                s16x8 bl = *(const s16x8*)(smem + SM_RL + roff);
                #pragma unroll
                for (int i = 0; i < 8; ++i) {
                    s16x8 ah = *(const s16x8*)(smem + SM_EH + eoff + i*2048);
                    acc[i] = __builtin_amdgcn_mfma_f32_16x16x32_bf16(ah, bh, acc[i], 0, 0, 0);
                    acc[i] = __builtin_amdgcn_mfma_f32_16x16x32_bf16(ah, bl, acc[i], 0, 0, 0);
                }
            }

            // approx scores C = se - 2*A (stored back into acc regs); chunk min
            float mi[8];
            float m = INFINITY;
            #pragma unroll
            for (int i = 0; i < 8; ++i) {
                #pragma unroll
                for (int rg = 0; rg < 4; ++rg)
                    acc[i][rg] = selds[i*16 + lhi*4 + rg] - 2.0f*acc[i][rg];
                float a = fminf(fminf(acc[i][0], acc[i][1]), fminf(acc[i][2], acc[i][3]));
                mi[i] = a;
                m = fminf(m, a);
            }
            m = fminf(m, __shfl_xor(m, 16, 64));
            m = fminf(m, __shfl_xor(m, 32, 64));
            const float thr = fminf(m_run, m) + band;
            m_run = fminf(m_run, m);

            // push candidates (group-skip via __any; queue consumed once per stage)
            #pragma unroll
            for (int i = 0; i < 8; ++i) {
                if (__any(mi[i] <= thr)) {
                    #pragma unroll
                    for (int rg = 0; rg < 4; ++rg) {
                        if (acc[i][rg] <= thr) {
                            int kl = i*16 + lhi*4 + rg;
                            int kg = c*KTB + kl;
                            int slot = atomicAdd(qcnt, 1);
                            if (slot < QMAX) {
                                que[slot] = ((unsigned)nlocal << 10) | (unsigned)kg;
                            } else {   // overflow fallback (rare, correct)
                                float d2e = vq_rescore(rf, lds_sr[nlocal], selds[kl],
                                                       emb_s, nlocal, kg);
                                unsigned long long pk =
                                    ((unsigned long long)__float_as_uint(d2e) << 32) | (unsigned)kg;
                                atomicMin(&best64[nlocal], pk);
                            }
                        }
                    }
                }
            }
            __syncthreads();                       // E(c) consumed; pushes visible
            if (pre) {
                ((float4*)(smem + SM_EH))[tid]     = h0;
                ((float4*)(smem + SM_EH))[tid+256] = h1;
                ((float4*)(smem + SM_EH))[tid+512] = h2;
                ((float4*)(smem + SM_EH))[tid+768] = h3;
                if (tid < KTB) selds[tid] = sepre;
            }
        }

        // ---- per-stage parallel rescore of queued candidates ----
        const int cnt = min(qcnt[0], QMAX);
        for (int e = tid; e < cnt; e += 256) {
            unsigned ent = que[e];
            int nn = (int)(ent >> 10);
            int kg = (int)(ent & 1023);
            float sek = se_g[s*Kn + kg];
            float d2e = vq_rescore(rf, lds_sr[nn], sek, emb_s, nn, kg);
            unsigned long long pk =
                ((unsigned long long)__float_as_uint(d2e) << 32) | (unsigned)kg;
            atomicMin(&best64[nn], pk);
        }
        __syncthreads();                           // best64 final; queue dead

        // ---- finalize stage: idx/used; residual update ----
        if (tid < 64) {
            int bk = (int)(best64[tid] & 0xFFFFFFFFull) & (Kn - 1);
            bkL[tid] = bk;
            out_idx[s*Nn + n0 + tid] = (float)bk;
            used_g[s*Kn + bk] = 1.0f;
            best64[tid] = ~0ULL;                   // reset for next stage
        }
        if (tid == 0) qcnt[0] = 0;
        __syncthreads();                           // bkL visible

        const float* ep = emb_s + (size_t)bkL[nl]*Dn;
        if (s < NCB-1) {
            float nv[16];
            #pragma unroll
            for (int j = 0; j < 16; ++j) {
                int d = dg*16 + j;
                float rv = rf[d*64 + nl];
                float q  = ep[d];
                float diff = rv - q;               // loss uses raw q
                lsum = fmaf(diff, diff, lsum);
                float qst = rv + (q - rv);         // straight-through, fp32-faithful
                nv[j] = rv - qst;
                rf[d*64 + nl] = nv[j];
            }
            // sr partials of new residual
            float a0=0.f,a1=0.f,a2=0.f,a3=0.f;
            #pragma unroll
            for (int j = 0; j < 16; j += 4) {
                a0 = fmaf(nv[j+0], nv[j+0], a0);
                a1 = fmaf(nv[j+1], nv[j+1], a1);
                a2 = fmaf(nv[j+2], nv[j+2], a2);
                a3 = fmaf(nv[j+3], nv[j+3], a3);
            }
            srpart[dg*64 + nl] = (a0+a1)+(a2+a3);
            // bf16 split of new residual -> RH/RL
            unsigned short hi[16], lo[16];
            #pragma unroll
            for (int j = 0; j < 16; ++j) {
                hi[j] = f2bf(nv[j]);
                lo[j] = f2bf(nv[j] - bf2f(hi[j]));
            }
            s16x8 ph0, ph1, pl0, pl1;
            #pragma unroll
            for (int j = 0; j < 8; ++j) {
                ph0[j] = (short)hi[j];   ph1[j] = (short)hi[j+8];
                pl0[j] = (short)lo[j];   pl1[j] = (short)lo[j+8];
            }
            const int s0 = dg*2, s1 = dg*2 + 1, nx = nl & 7;
            *(s16x8*)(smem + SM_RH + nl*128 + ((s0 ^ nx) << 4)) = ph0;
            *(s16x8*)(smem + SM_RH + nl*128 + ((s1 ^ nx) << 4)) = ph1;
            *(s16x8*)(smem + SM_RL + nl*128 + ((s0 ^ nx) << 4)) = pl0;
            *(s16x8*)(smem + SM_RL + nl*128 + ((s1 ^ nx) << 4)) = pl1;
            __syncthreads();                       // srpart ready
            if (tid < 64)
                lds_sr[tid] = (srpart[tid] + srpart[64+tid])
                            + (srpart[128+tid] + srpart[192+tid]);
            // next stage's chunk-0 top barrier covers lds_sr/RH/RL visibility
        } else {
            // final stage: qt = x - res_final, written directly
            const int n = n0 + nl;
            const int b = n / Tn, t = n % Tn;
            const float* xp = x + b*(Dn*Tn) + t;
            float* qp = out_qt + b*(Dn*Tn) + t;
            #pragma unroll
            for (int j = 0; j < 16; ++j) {
                int d = dg*16 + j;
                float rv = rf[d*64 + nl];
                float q  = ep[d];
                float diff = rv - q;
                lsum = fmaf(diff, diff, lsum);
                float qst = rv + (q - rv);
                float rn = rv - qst;
                qp[d*Tn] = xp[d*Tn] - rn;
            }
        }
    }

    // ---- loss reduce (once for all 8 stages) ----
    float* red = (float*)(smem + SM_QUE);          // queue dead
    red[tid] = lsum;
    __syncthreads();
    for (int s2 = 128; s2 > 0; s2 >>= 1) {
        if (tid < s2) red[tid] += red[tid + s2];
        __syncthreads();
    }
    if (tid == 0) atomicAdd(loss_acc, red[0]);
}

// ---------- scalars: (commit+codebook)/NCB and utilization (fp32 out) ----------
__global__ void vq_scalars(const float* __restrict__ used, const float* __restrict__ loss_acc,
                           float* __restrict__ out)
{
    __shared__ float red[256];
    float s = 0.f;
    for (int j = threadIdx.x; j < NCB*Kn; j += 256) s += used[j];
    red[threadIdx.x] = s;
    __syncthreads();
    for (int st = 128; st > 0; st >>= 1) {
        if (threadIdx.x < st) red[threadIdx.x] += red[threadIdx.x + st];
        __syncthreads();
    }
    if (threadIdx.x == 0) {
        float sumsq = loss_acc[0];
        float total_loss = 2.0f * sumsq / (float)(Nn*Dn);  // sum over stages of commit+codebook
        out[OUT_SC_OFF + 0] = total_loss / (float)NCB;
        out[OUT_SC_OFF + 1] = red[0] / (float)(NCB*Kn);
    }
}

extern "C" void kernel_launch(void* const* d_in, const int* in_sizes, int n_in,
                              void* d_out, int out_size, void* d_ws, size_t ws_size,
                              hipStream_t stream)
{
    const float* x      = (const float*)d_in[0];
    const float* embeds = (const float*)d_in[1];
    float* out = (float*)d_out;
    char* ws = (char*)d_ws;

    char*  ehi   = ws + WS_EHI;
    float* se    = (float*)(ws + WS_SE);
    float* used  = (float*)(ws + WS_USED);
    float* loss  = (float*)(ws + WS_LOSS);
    float* semax = (float*)(ws + WS_SEMAX);

    // zero used + loss + semax (contiguous)
    hipMemsetAsync(used, 0, (size_t)NCB*Kn*sizeof(float) + 48, stream);

    vq_se<<<(NCB*Kn + 255)/256, 256, 0, stream>>>(embeds, se, semax);
    vq_ebf<<<256, 256, 0, stream>>>(embeds, ehi);

    vq_mega<<<NBLK, 256, 0, stream>>>(x, embeds, ehi, se, semax,
                                      out + OUT_QT_OFF, out + OUT_IDX_OFF,
                                      used, loss);

    vq_scalars<<<1, 256, 0, stream>>>(used, loss, out);
}

// Round 13
// 402.873 us; speedup vs baseline: 1.7194x; 1.7194x over previous
//
#include <hip/hip_runtime.h>
#include <hip/hip_bf16.h>
#include <math.h>

// Problem constants
#define Bn   16
#define Dn   64
#define Tn   3000
#define Nn   (Bn*Tn)          // 48000
#define NCB  8
#define Kn   1024
#define KTB  64               // codes per k-chunk (LDS staged)
#define NCHK (Kn/KTB)         // 16 chunks per codebook
#define NTB  64               // n per block
#define NBLK (Nn/NTB)         // 750 (exact) <= 768 = 256CU x 3 blocks
#define QMAX 512              // per-stage queue capacity (typ ~70 used)

// LDS layout (bytes), total 44304 -> 3 blocks/CU
#define SM_RH   0                      // bf16 [64n][64d] swizzled = 8192
#define SM_RL   8192                   // 8192
#define SM_EH   16384                  // bf16 [64k][64d] swizzled = 8192 (hi only)
#define SM_RF   24576                  // float [64d][64n] = 16384 (exact residual)
#define SM_SE   40960                  // float[64] chunk selds = 256
#define SM_SR   41216                  // float[64] = 256
#define SM_BEST 41472                  // u64[64] = 512
#define SM_QCNT 41984                  // int (+pad) = 16
#define SM_QUE  42000                  // u32[QMAX] = 2048
#define SM_BK   44048                  // int[64] = 256
#define SM_TOT  44304
// aliases on SM_QUE (queue dead then): srpart[256]f, red[256]f

// Workspace byte offsets
#define WS_EHI   12288000                      // u8[8cb][16chk][64k][128B] pre-swizzled bf16 hi
#define WS_SE    13336576                      // float[NCB*Kn]
#define WS_USED  13369344                      // float[NCB*Kn]
#define WS_LOSS  13402112                      // float[1]
#define WS_SEMAX 13402128                      // float[8]

// Output element offsets (fp32 elements)
#define OUT_QT_OFF  0
#define OUT_IDX_OFF 3072000
#define OUT_SC_OFF  3456000

typedef __attribute__((ext_vector_type(4))) float f32x4;
typedef __attribute__((ext_vector_type(8))) short s16x8;

__device__ __forceinline__ unsigned short f2bf(float x) {   // RNE bf16 bits
    unsigned int u = __float_as_uint(x);
    unsigned int r = (u + 0x7FFFu + ((u >> 16) & 1u)) >> 16;
    return (unsigned short)r;
}
__device__ __forceinline__ float bf2f(unsigned short h) {
    return __uint_as_float(((unsigned int)h) << 16);
}

// ---------- precompute ||e_k||^2 + per-codebook max ----------
__global__ void vq_se(const float* __restrict__ emb, float* __restrict__ se,
                      float* __restrict__ semax)
{
    int r = blockIdx.x * 256 + threadIdx.x;   // 0..8191
    if (r < NCB*Kn) {
        const float* p = emb + r*Dn;
        float a0=0.f, a1=0.f, a2=0.f, a3=0.f;
        #pragma unroll
        for (int d = 0; d < Dn; d += 4) {
            a0 = fmaf(p[d+0], p[d+0], a0);
            a1 = fmaf(p[d+1], p[d+1], a1);
            a2 = fmaf(p[d+2], p[d+2], a2);
            a3 = fmaf(p[d+3], p[d+3], a3);
        }
        float v = (a0+a1)+(a2+a3);
        se[r] = v;
        atomicMax((int*)&semax[r >> 10], __float_as_int(v));  // v >= 0: int order = float order
    }
}

// ---------- precompute bf16 hi split of all codebooks, pre-swizzled ----------
__global__ void vq_ebf(const float* __restrict__ emb, char* __restrict__ ehi)
{
    int idx = blockIdx.x * 256 + threadIdx.x;   // < 65536
    int r = idx >> 3;                            // cb*1024 + k
    int s = idx & 7;                             // dim slice
    const float* p = emb + (size_t)r*Dn + s*8;
    s16x8 hh;
    #pragma unroll
    for (int j = 0; j < 8; ++j) hh[j] = (short)f2bf(p[j]);
    int cb = r >> 10, kk = r & 1023, c = kk >> 6, kl = kk & 63;
    size_t off = (size_t)cb*131072 + (size_t)c*8192 + (size_t)kl*128 + ((s ^ (kl & 7)) << 4);
    *(s16x8*)(ehi + off) = hh;
}

// exact fp32 rescore: d2 = (sr - 2*dot) + sek  (identical chain since R8, verified)
__device__ __forceinline__
float vq_rescore(const float* rf, float sr, float sek,
                 const float* __restrict__ emb_cb, int n, int kg)
{
    const float4* ep = (const float4*)(emb_cb + (size_t)kg*Dn);
    float q0=0.f,q1=0.f,q2=0.f,q3=0.f;
    #pragma unroll 4
    for (int m = 0; m < 16; ++m) {
        float4 e4 = ep[m];
        q0 = fmaf(rf[(4*m+0)*64 + n], e4.x, q0);
        q1 = fmaf(rf[(4*m+1)*64 + n], e4.y, q1);
        q2 = fmaf(rf[(4*m+2)*64 + n], e4.z, q2);
        q3 = fmaf(rf[(4*m+3)*64 + n], e4.w, q3);
    }
    float dot = (q0+q1)+(q2+q3);
    return (sr - 2.0f*dot) + sek;
}

// ---------- mega kernel: all 8 stages fused, residual lives in LDS ----------
// grid NBLK, block 256 (4 waves). Wave w owns n-rows [w*16, w*16+16).
__global__ __launch_bounds__(256, 3)
void vq_mega(const float* __restrict__ x, const float* __restrict__ emb,
             const char* __restrict__ ehib, const float* __restrict__ se_g,
             const float* __restrict__ semax_g,
             float* __restrict__ out_qt, float* __restrict__ out_idx,
             float* __restrict__ used_g, float* __restrict__ loss_acc)
{
    __shared__ __align__(16) char smem[SM_TOT];
    float*  rf     = (float*)(smem + SM_RF);
    float*  selds  = (float*)(smem + SM_SE);
    float*  lds_sr = (float*)(smem + SM_SR);
    unsigned long long* best64 = (unsigned long long*)(smem + SM_BEST);
    int*    qcnt   = (int*)(smem + SM_QCNT);
    unsigned int* que = (unsigned int*)(smem + SM_QUE);
    float*  srpart = (float*)(smem + SM_QUE);    // alias (stage transitions only)
    int*    bkL    = (int*)(smem + SM_BK);

    const int tid = threadIdx.x;
    const int n0 = blockIdx.x * NTB;
    const int lane = tid & 63, w = tid >> 6;
    const int lrow = lane & 15, lhi = lane >> 4;
    const int nl = tid & 63;
    const int dg = tid >> 6;
    const float4* hsrc = (const float4*)ehib;

    // ---- prologue: stage R from x (fp32 rf + bf16 hi/lo swizzled) + sr partials ----
    {
        const int n = n0 + nl;
        const int b = n / Tn, t = n % Tn;
        const float* gp = x + b*(Dn*Tn) + t;
        float v[16];
        #pragma unroll
        for (int j = 0; j < 16; ++j) v[j] = gp[(dg*16 + j)*Tn];
        float a0=0.f,a1=0.f,a2=0.f,a3=0.f;
        #pragma unroll
        for (int j = 0; j < 16; j += 4) {
            a0 = fmaf(v[j+0], v[j+0], a0);
            a1 = fmaf(v[j+1], v[j+1], a1);
            a2 = fmaf(v[j+2], v[j+2], a2);
            a3 = fmaf(v[j+3], v[j+3], a3);
        }
        srpart[dg*64 + nl] = (a0+a1)+(a2+a3);
        unsigned short hi[16], lo[16];
        #pragma unroll
        for (int j = 0; j < 16; ++j) {
            rf[(dg*16 + j)*64 + nl] = v[j];
            hi[j] = f2bf(v[j]);
            lo[j] = f2bf(v[j] - bf2f(hi[j]));
        }
        s16x8 ph0, ph1, pl0, pl1;
        #pragma unroll
        for (int j = 0; j < 8; ++j) {
            ph0[j] = (short)hi[j];   ph1[j] = (short)hi[j+8];
            pl0[j] = (short)lo[j];   pl1[j] = (short)lo[j+8];
        }
        const int s0 = dg*2, s1 = dg*2 + 1, nx = nl & 7;
        *(s16x8*)(smem + SM_RH + nl*128 + ((s0 ^ nx) << 4)) = ph0;
        *(s16x8*)(smem + SM_RH + nl*128 + ((s1 ^ nx) << 4)) = ph1;
        *(s16x8*)(smem + SM_RL + nl*128 + ((s0 ^ nx) << 4)) = pl0;
        *(s16x8*)(smem + SM_RL + nl*128 + ((s1 ^ nx) << 4)) = pl1;
    }
    if (tid < 64) best64[tid] = ~0ULL;
    if (tid == 0) qcnt[0] = 0;
    __syncthreads();                               // srpart ready
    if (tid < 64)
        lds_sr[tid] = (srpart[tid] + srpart[64+tid]) + (srpart[128+tid] + srpart[192+tid]);
    // stage E(cb0, chunk0): 8 KB linear copy of pre-swizzled hi
    ((float4*)(smem + SM_EH))[tid]       = hsrc[tid];
    ((float4*)(smem + SM_EH))[tid+256]   = hsrc[tid+256];
    if (tid < KTB) selds[tid] = se_g[tid];

    float lsum = 0.f;
    const int nlocal = w*16 + lrow;

    // ================= stage loop =================
    for (int s = 0; s < NCB; ++s) {
        const float* emb_s = emb + (size_t)s*(Kn*Dn);
        const float semx = semax_g[s];
        float m_run = INFINITY;
        float band = 0.f;

        // ---- chunk loop (16 x 64 codes) ----
        for (int c = 0; c < NCHK; ++c) {
            __syncthreads();                       // E(c)/selds(c)/RH/RL/lds_sr ready
            if (c == 0)                            // per-n rigorous candidate band
                band = 0.0095f * sqrtf(semx * lds_sr[nlocal]) + 2e-4f;

            // prefetch next E chunk (or next codebook's chunk 0) into regs
            const bool pre = (c < NCHK-1) || (s < NCB-1);
            float4 h0, h1; float sepre = 0.f;
            if (pre) {
                size_t nb = (c < NCHK-1) ? ((size_t)s*8192 + (size_t)(c+1)*512)
                                         : ((size_t)(s+1)*8192);
                h0 = hsrc[nb + tid]; h1 = hsrc[nb + 256 + tid];
                if (tid < KTB)
                    sepre = se_g[(c < NCHK-1) ? (s*Kn + (c+1)*KTB + tid)
                                              : ((s+1)*Kn + tid)];
            }

            // MFMA: acc[i] = eh . (rh + rl)  (2-pass split, E-hi only)
            f32x4 acc[4];
            #pragma unroll
            for (int i = 0; i < 4; ++i) acc[i] = (f32x4){0.f,0.f,0.f,0.f};
            #pragma unroll
            for (int ks = 0; ks < 2; ++ks) {
                const int sdim = ks*4 + lhi;
                const int swz = ((sdim ^ (lrow & 7)) << 4);
                const size_t roff = (size_t)(w*16 + lrow)*128 + swz;
                const size_t eoff = (size_t)lrow*128 + swz;
                s16x8 bh = *(const s16x8*)(smem + SM_RH + roff);
                s16x8 bl = *(const s16x8*)(smem + SM_RL + roff);
                #pragma unroll
                for (int i = 0; i < 4; ++i) {
                    s16x8 ah = *(const s16x8*)(smem + SM_EH + eoff + i*2048);
                    acc[i] = __builtin_amdgcn_mfma_f32_16x16x32_bf16(ah, bh, acc[i], 0, 0, 0);
                    acc[i] = __builtin_amdgcn_mfma_f32_16x16x32_bf16(ah, bl, acc[i], 0, 0, 0);
                }
            }

            // approx scores C = se - 2*A (stored back into acc regs); chunk min
            float mi[4];
            float m = INFINITY;
            #pragma unroll
            for (int i = 0; i < 4; ++i) {
                #pragma unroll
                for (int rg = 0; rg < 4; ++rg)
                    acc[i][rg] = selds[i*16 + lhi*4 + rg] - 2.0f*acc[i][rg];
                float a = fminf(fminf(acc[i][0], acc[i][1]), fminf(acc[i][2], acc[i][3]));
                mi[i] = a;
                m = fminf(m, a);
            }
            m = fminf(m, __shfl_xor(m, 16, 64));
            m = fminf(m, __shfl_xor(m, 32, 64));
            const float thr = fminf(m_run, m) + band;
            m_run = fminf(m_run, m);

            // push candidates (group-skip via __any; queue consumed once per stage)
            #pragma unroll
            for (int i = 0; i < 4; ++i) {
                if (__any(mi[i] <= thr)) {
                    #pragma unroll
                    for (int rg = 0; rg < 4; ++rg) {
                        if (acc[i][rg] <= thr) {
                            int kl = i*16 + lhi*4 + rg;
                            int kg = c*KTB + kl;
                            int slot = atomicAdd(qcnt, 1);
                            if (slot < QMAX) {
                                que[slot] = ((unsigned)nlocal << 10) | (unsigned)kg;
                            } else {   // overflow fallback (rare, correct)
                                float d2e = vq_rescore(rf, lds_sr[nlocal], selds[kl],
                                                       emb_s, nlocal, kg);
                                unsigned long long pk =
                                    ((unsigned long long)__float_as_uint(d2e) << 32) | (unsigned)kg;
                                atomicMin(&best64[nlocal], pk);
                            }
                        }
                    }
                }
            }
            __syncthreads();                       // E(c) consumed; pushes visible
            if (pre) {
                ((float4*)(smem + SM_EH))[tid]     = h0;
                ((float4*)(smem + SM_EH))[tid+256] = h1;
                if (tid < KTB) selds[tid] = sepre;
            }
        }

        // ---- per-stage parallel rescore of queued candidates ----
        const int cnt = min(qcnt[0], QMAX);
        for (int e = tid; e < cnt; e += 256) {
            unsigned ent = que[e];
            int nn = (int)(ent >> 10);
            int kg = (int)(ent & 1023);
            float sek = se_g[s*Kn + kg];
            float d2e = vq_rescore(rf, lds_sr[nn], sek, emb_s, nn, kg);
            unsigned long long pk =
                ((unsigned long long)__float_as_uint(d2e) << 32) | (unsigned)kg;
            atomicMin(&best64[nn], pk);
        }
        __syncthreads();                           // best64 final; queue dead

        // ---- finalize stage: idx/used; residual update ----
        if (tid < 64) {
            int bk = (int)(best64[tid] & 0xFFFFFFFFull) & (Kn - 1);
            bkL[tid] = bk;
            out_idx[s*Nn + n0 + tid] = (float)bk;
            used_g[s*Kn + bk] = 1.0f;
            best64[tid] = ~0ULL;                   // reset for next stage
        }
        if (tid == 0) qcnt[0] = 0;
        __syncthreads();                           // bkL visible

        const float* ep = emb_s + (size_t)bkL[nl]*Dn;
        if (s < NCB-1) {
            float nv[16];
            #pragma unroll
            for (int j = 0; j < 16; ++j) {
                int d = dg*16 + j;
                float rv = rf[d*64 + nl];
                float q  = ep[d];
                float diff = rv - q;               // loss uses raw q
                lsum = fmaf(diff, diff, lsum);
                float qst = rv + (q - rv);         // straight-through, fp32-faithful
                nv[j] = rv - qst;
                rf[d*64 + nl] = nv[j];
            }
            // sr partials of new residual
            float a0=0.f,a1=0.f,a2=0.f,a3=0.f;
            #pragma unroll
            for (int j = 0; j < 16; j += 4) {
                a0 = fmaf(nv[j+0], nv[j+0], a0);
                a1 = fmaf(nv[j+1], nv[j+1], a1);
                a2 = fmaf(nv[j+2], nv[j+2], a2);
                a3 = fmaf(nv[j+3], nv[j+3], a3);
            }
            srpart[dg*64 + nl] = (a0+a1)+(a2+a3);
            // bf16 split of new residual -> RH/RL
            unsigned short hi[16], lo[16];
            #pragma unroll
            for (int j = 0; j < 16; ++j) {
                hi[j] = f2bf(nv[j]);
                lo[j] = f2bf(nv[j] - bf2f(hi[j]));
            }
            s16x8 ph0, ph1, pl0, pl1;
            #pragma unroll
            for (int j = 0; j < 8; ++j) {
                ph0[j] = (short)hi[j];   ph1[j] = (short)hi[j+8];
                pl0[j] = (short)lo[j];   pl1[j] = (short)lo[j+8];
            }
            const int s0 = dg*2, s1 = dg*2 + 1, nx = nl & 7;
            *(s16x8*)(smem + SM_RH + nl*128 + ((s0 ^ nx) << 4)) = ph0;
            *(s16x8*)(smem + SM_RH + nl*128 + ((s1 ^ nx) << 4)) = ph1;
            *(s16x8*)(smem + SM_RL + nl*128 + ((s0 ^ nx) << 4)) = pl0;
            *(s16x8*)(smem + SM_RL + nl*128 + ((s1 ^ nx) << 4)) = pl1;
            __syncthreads();                       // srpart ready
            if (tid < 64)
                lds_sr[tid] = (srpart[tid] + srpart[64+tid])
                            + (srpart[128+tid] + srpart[192+tid]);
            // next stage's chunk-0 top barrier covers lds_sr/RH/RL visibility
        } else {
            // final stage: qt = x - res_final, written directly
            const int n = n0 + nl;
            const int b = n / Tn, t = n % Tn;
            const float* xp = x + b*(Dn*Tn) + t;
            float* qp = out_qt + b*(Dn*Tn) + t;
            #pragma unroll
            for (int j = 0; j < 16; ++j) {
                int d = dg*16 + j;
                float rv = rf[d*64 + nl];
                float q  = ep[d];
                float diff = rv - q;
                lsum = fmaf(diff, diff, lsum);
                float qst = rv + (q - rv);
                float rn = rv - qst;
                qp[d*Tn] = xp[d*Tn] - rn;
            }
        }
    }

    // ---- loss reduce (once for all 8 stages) ----
    float* red = (float*)(smem + SM_QUE);          // queue dead
    red[tid] = lsum;
    __syncthreads();
    for (int s2 = 128; s2 > 0; s2 >>= 1) {
        if (tid < s2) red[tid] += red[tid + s2];
        __syncthreads();
    }
    if (tid == 0) atomicAdd(loss_acc, red[0]);
}

// ---------- scalars: (commit+codebook)/NCB and utilization (fp32 out) ----------
__global__ void vq_scalars(const float* __restrict__ used, const float* __restrict__ loss_acc,
                           float* __restrict__ out)
{
    __shared__ float red[256];
    float s = 0.f;
    for (int j = threadIdx.x; j < NCB*Kn; j += 256) s += used[j];
    red[threadIdx.x] = s;
    __syncthreads();
    for (int st = 128; st > 0; st >>= 1) {
        if (threadIdx.x < st) red[threadIdx.x] += red[threadIdx.x + st];
        __syncthreads();
    }
    if (threadIdx.x == 0) {
        float sumsq = loss_acc[0];
        float total_loss = 2.0f * sumsq / (float)(Nn*Dn);  // sum over stages of commit+codebook
        out[OUT_SC_OFF + 0] = total_loss / (float)NCB;
        out[OUT_SC_OFF + 1] = red[0] / (float)(NCB*Kn);
    }
}

extern "C" void kernel_launch(void* const* d_in, const int* in_sizes, int n_in,
                              void* d_out, int out_size, void* d_ws, size_t ws_size,
                              hipStream_t stream)
{
    const float* x      = (const float*)d_in[0];
    const float* embeds = (const float*)d_in[1];
    float* out = (float*)d_out;
    char* ws = (char*)d_ws;

    char*  ehi   = ws + WS_EHI;
    float* se    = (float*)(ws + WS_SE);
    float* used  = (float*)(ws + WS_USED);
    float* loss  = (float*)(ws + WS_LOSS);
    float* semax = (float*)(ws + WS_SEMAX);

    // zero used + loss + semax (contiguous)
    hipMemsetAsync(used, 0, (size_t)NCB*Kn*sizeof(float) + 48, stream);

    vq_se<<<(NCB*Kn + 255)/256, 256, 0, stream>>>(embeds, se, semax);
    vq_ebf<<<256, 256, 0, stream>>>(embeds, ehi);

    vq_mega<<<NBLK, 256, 0, stream>>>(x, embeds, ehi, se, semax,
                                      out + OUT_QT_OFF, out + OUT_IDX_OFF,
                                      used, loss);

    vq_scalars<<<1, 256, 0, stream>>>(used, loss, out);
}

// Round 14
// 385.803 us; speedup vs baseline: 1.7954x; 1.0442x over previous
//
#include <hip/hip_runtime.h>
#include <hip/hip_bf16.h>
#include <math.h>

// Problem constants
#define Bn   16
#define Dn   64
#define Tn   3000
#define Nn   (Bn*Tn)          // 48000
#define NCB  8
#define Kn   1024
#define KTB  64               // codes per k-chunk
#define NCHK (Kn/KTB)         // 16 chunks per codebook
#define NTB  64               // n per block
#define NBLK (Nn/NTB)         // 750 (exact)
#define QMAX 512              // per-stage queue capacity (typ ~70-150 used)

// LDS layout (bytes), total 39952 -> LDS allows 4 blocks/CU (grid gives ~3)
#define SM_RH    0                     // bf16 [64n][64d] swizzled = 8192
#define SM_RL    8192                  // 8192
#define SM_RF    16384                 // float [64d][64n] = 16384 (exact residual)
#define SM_SESTG 32768                 // float[1024] whole-stage se = 4096
#define SM_SR    36864                 // float[64] = 256
#define SM_BEST  37120                 // u64[64] = 512
#define SM_QCNT  37632                 // int (+pad) = 16
#define SM_QUE   37648                 // u32[QMAX] = 2048
#define SM_BK    39696                 // int[64] = 256
#define SM_TOT   39952
// aliases on SM_QUE (queue dead then): srpart[256]f, red[256]f

// Workspace byte offsets
#define WS_EHI   12288000                      // u8[8cb][16chk][8frag][16lrow][4lhi][16B] fragment-major bf16 hi
#define WS_SE    13336576                      // float[NCB*Kn]
#define WS_USED  13369344                      // float[NCB*Kn]
#define WS_LOSS  13402112                      // float[1]
#define WS_SEMAX 13402128                      // float[8]

// Output element offsets (fp32 elements)
#define OUT_QT_OFF  0
#define OUT_IDX_OFF 3072000
#define OUT_SC_OFF  3456000

typedef __attribute__((ext_vector_type(4))) float f32x4;
typedef __attribute__((ext_vector_type(8))) short s16x8;

__device__ __forceinline__ unsigned short f2bf(float x) {   // RNE bf16 bits
    unsigned int u = __float_as_uint(x);
    unsigned int r = (u + 0x7FFFu + ((u >> 16) & 1u)) >> 16;
    return (unsigned short)r;
}
__device__ __forceinline__ float bf2f(unsigned short h) {
    return __uint_as_float(((unsigned int)h) << 16);
}

// ---------- precompute ||e_k||^2 + per-codebook max ----------
__global__ void vq_se(const float* __restrict__ emb, float* __restrict__ se,
                      float* __restrict__ semax)
{
    int r = blockIdx.x * 256 + threadIdx.x;   // 0..8191
    if (r < NCB*Kn) {
        const float* p = emb + r*Dn;
        float a0=0.f, a1=0.f, a2=0.f, a3=0.f;
        #pragma unroll
        for (int d = 0; d < Dn; d += 4) {
            a0 = fmaf(p[d+0], p[d+0], a0);
            a1 = fmaf(p[d+1], p[d+1], a1);
            a2 = fmaf(p[d+2], p[d+2], a2);
            a3 = fmaf(p[d+3], p[d+3], a3);
        }
        float v = (a0+a1)+(a2+a3);
        se[r] = v;
        atomicMax((int*)&semax[r >> 10], __float_as_int(v));  // v >= 0: int order = float order
    }
}

// ---------- precompute bf16 hi of codebooks, FRAGMENT-MAJOR layout ----------
// MFMA A-frag for lane (lrow,lhi), sub-k ks, tile i reads 16B at:
//   cb*131072 + c*8192 + ((i*2+ks)*16 + lrow)*64 + lhi*16
__global__ void vq_ebf(const float* __restrict__ emb, char* __restrict__ ehi)
{
    int idx = blockIdx.x * 256 + threadIdx.x;   // < 65536
    int r = idx >> 3;                            // cb*1024 + k
    int sdim = idx & 7;                          // ks*4 + lhi
    const float* p = emb + (size_t)r*Dn + sdim*8;
    s16x8 hh;
    #pragma unroll
    for (int j = 0; j < 8; ++j) hh[j] = (short)f2bf(p[j]);
    int cb = r >> 10, kk = r & 1023, c = kk >> 6, kl = kk & 63;
    int i = kl >> 4, lrow = kl & 15, ks = sdim >> 2, lhi = sdim & 3;
    size_t off = (size_t)cb*131072 + (size_t)c*8192
               + (size_t)((i*2 + ks)*16 + lrow)*64 + lhi*16;
    *(s16x8*)(ehi + off) = hh;
}

// exact fp32 rescore: d2 = (sr - 2*dot) + sek  (identical chain since R8, verified)
__device__ __forceinline__
float vq_rescore(const float* rf, float sr, float sek,
                 const float* __restrict__ emb_cb, int n, int kg)
{
    const float4* ep = (const float4*)(emb_cb + (size_t)kg*Dn);
    float q0=0.f,q1=0.f,q2=0.f,q3=0.f;
    #pragma unroll 4
    for (int m = 0; m < 16; ++m) {
        float4 e4 = ep[m];
        q0 = fmaf(rf[(4*m+0)*64 + n], e4.x, q0);
        q1 = fmaf(rf[(4*m+1)*64 + n], e4.y, q1);
        q2 = fmaf(rf[(4*m+2)*64 + n], e4.z, q2);
        q3 = fmaf(rf[(4*m+3)*64 + n], e4.w, q3);
    }
    float dot = (q0+q1)+(q2+q3);
    return (sr - 2.0f*dot) + sek;
}

// ---------- mega kernel: all 8 stages fused, residual in LDS, barrier-free chunk loop ----------
// grid NBLK, block 256 (4 waves). Wave w owns n-rows [w*16, w*16+16).
__global__ __launch_bounds__(256, 3)
void vq_mega(const float* __restrict__ x, const float* __restrict__ emb,
             const char* __restrict__ ehib, const float* __restrict__ se_g,
             const float* __restrict__ semax_g,
             float* __restrict__ out_qt, float* __restrict__ out_idx,
             float* __restrict__ used_g, float* __restrict__ loss_acc)
{
    __shared__ __align__(16) char smem[SM_TOT];
    float*  rf     = (float*)(smem + SM_RF);
    float*  sestg  = (float*)(smem + SM_SESTG);  // whole stage's ||e||^2
    float*  lds_sr = (float*)(smem + SM_SR);
    unsigned long long* best64 = (unsigned long long*)(smem + SM_BEST);
    int*    qcnt   = (int*)(smem + SM_QCNT);
    unsigned int* que = (unsigned int*)(smem + SM_QUE);
    float*  srpart = (float*)(smem + SM_QUE);    // alias (stage transitions only)
    int*    bkL    = (int*)(smem + SM_BK);

    const int tid = threadIdx.x;
    const int n0 = blockIdx.x * NTB;
    const int lane = tid & 63, w = tid >> 6;
    const int lrow = lane & 15, lhi = lane >> 4;
    const int nl = tid & 63;
    const int dg = tid >> 6;
    const int laneoff = lrow*64 + lhi*16;        // A-frag per-lane byte offset

    // ---- prologue: stage R from x (fp32 rf + bf16 hi/lo swizzled) + sr partials ----
    {
        const int n = n0 + nl;
        const int b = n / Tn, t = n % Tn;
        const float* gp = x + b*(Dn*Tn) + t;
        float v[16];
        #pragma unroll
        for (int j = 0; j < 16; ++j) v[j] = gp[(dg*16 + j)*Tn];
        float a0=0.f,a1=0.f,a2=0.f,a3=0.f;
        #pragma unroll
        for (int j = 0; j < 16; j += 4) {
            a0 = fmaf(v[j+0], v[j+0], a0);
            a1 = fmaf(v[j+1], v[j+1], a1);
            a2 = fmaf(v[j+2], v[j+2], a2);
            a3 = fmaf(v[j+3], v[j+3], a3);
        }
        srpart[dg*64 + nl] = (a0+a1)+(a2+a3);
        unsigned short hi[16], lo[16];
        #pragma unroll
        for (int j = 0; j < 16; ++j) {
            rf[(dg*16 + j)*64 + nl] = v[j];
            hi[j] = f2bf(v[j]);
            lo[j] = f2bf(v[j] - bf2f(hi[j]));
        }
        s16x8 ph0, ph1, pl0, pl1;
        #pragma unroll
        for (int j = 0; j < 8; ++j) {
            ph0[j] = (short)hi[j];   ph1[j] = (short)hi[j+8];
            pl0[j] = (short)lo[j];   pl1[j] = (short)lo[j+8];
        }
        const int s0 = dg*2, s1 = dg*2 + 1, nx = nl & 7;
        *(s16x8*)(smem + SM_RH + nl*128 + ((s0 ^ nx) << 4)) = ph0;
        *(s16x8*)(smem + SM_RH + nl*128 + ((s1 ^ nx) << 4)) = ph1;
        *(s16x8*)(smem + SM_RL + nl*128 + ((s0 ^ nx) << 4)) = pl0;
        *(s16x8*)(smem + SM_RL + nl*128 + ((s1 ^ nx) << 4)) = pl1;
    }
    if (tid < 64) best64[tid] = ~0ULL;
    if (tid == 0) qcnt[0] = 0;
    __syncthreads();                               // srpart ready
    if (tid < 64)
        lds_sr[tid] = (srpart[tid] + srpart[64+tid]) + (srpart[128+tid] + srpart[192+tid]);
    *(float4*)&sestg[tid*4] = *(const float4*)&se_g[tid*4];   // stage-0 se
    __syncthreads();                               // lds_sr/sestg ready; srpart dead

    float lsum = 0.f;
    const int nlocal = w*16 + lrow;

    // ================= stage loop =================
    for (int s = 0; s < NCB; ++s) {
        const float* emb_s = emb + (size_t)s*(Kn*Dn);
        const char*  eh_s  = ehib + (size_t)s*131072;
        const float semx = semax_g[s];
        const float band = 0.0095f * sqrtf(semx * lds_sr[nlocal]) + 2e-4f;
        float m_run = INFINITY;

        // ---- chunk loop: ZERO barriers (read-only LDS + atomics only) ----
        for (int c = 0; c < NCHK; ++c) {
            const char* ec = eh_s + ((size_t)c << 13);
            s16x8 ahf[2][4];
            #pragma unroll
            for (int ks = 0; ks < 2; ++ks)
                #pragma unroll
                for (int i = 0; i < 4; ++i)
                    ahf[ks][i] = *(const s16x8*)(ec + (((i<<1) + ks) << 10) + laneoff);

            f32x4 acc[4];
            #pragma unroll
            for (int i = 0; i < 4; ++i) acc[i] = (f32x4){0.f,0.f,0.f,0.f};
            #pragma unroll
            for (int ks = 0; ks < 2; ++ks) {
                const int sdim = ks*4 + lhi;
                const int swz = ((sdim ^ (lrow & 7)) << 4);
                const size_t roff = (size_t)(w*16 + lrow)*128 + swz;
                s16x8 bh = *(const s16x8*)(smem + SM_RH + roff);
                s16x8 bl = *(const s16x8*)(smem + SM_RL + roff);
                #pragma unroll
                for (int i = 0; i < 4; ++i) {
                    acc[i] = __builtin_amdgcn_mfma_f32_16x16x32_bf16(ahf[ks][i], bh, acc[i], 0, 0, 0);
                    acc[i] = __builtin_amdgcn_mfma_f32_16x16x32_bf16(ahf[ks][i], bl, acc[i], 0, 0, 0);
                }
            }

            // approx scores C = se - 2*A (in-place in acc); chunk min
            float mi[4];
            float m = INFINITY;
            #pragma unroll
            for (int i = 0; i < 4; ++i) {
                f32x4 se4 = *(const f32x4*)&sestg[c*64 + i*16 + lhi*4];
                #pragma unroll
                for (int rg = 0; rg < 4; ++rg)
                    acc[i][rg] = se4[rg] - 2.0f*acc[i][rg];
                float a = fminf(fminf(acc[i][0], acc[i][1]), fminf(acc[i][2], acc[i][3]));
                mi[i] = a;
                m = fminf(m, a);
            }
            m = fminf(m, __shfl_xor(m, 16, 64));
            m = fminf(m, __shfl_xor(m, 32, 64));
            const float thr = fminf(m_run, m) + band;
            m_run = fminf(m_run, m);

            // push candidates (group-skip via __any; queue consumed once per stage)
            #pragma unroll
            for (int i = 0; i < 4; ++i) {
                if (__any(mi[i] <= thr)) {
                    #pragma unroll
                    for (int rg = 0; rg < 4; ++rg) {
                        if (acc[i][rg] <= thr) {
                            int kl = i*16 + lhi*4 + rg;
                            int kg = c*KTB + kl;
                            int slot = atomicAdd(qcnt, 1);
                            if (slot < QMAX) {
                                que[slot] = ((unsigned)nlocal << 10) | (unsigned)kg;
                            } else {   // overflow fallback (rare, correct)
                                float d2e = vq_rescore(rf, lds_sr[nlocal], sestg[kg],
                                                       emb_s, nlocal, kg);
                                unsigned long long pk =
                                    ((unsigned long long)__float_as_uint(d2e) << 32) | (unsigned)kg;
                                atomicMin(&best64[nlocal], pk);
                            }
                        }
                    }
                }
            }
        }
        __syncthreads();                           // all pushes visible

        // ---- per-stage parallel rescore of queued candidates ----
        const int cnt = min(qcnt[0], QMAX);
        for (int e = tid; e < cnt; e += 256) {
            unsigned ent = que[e];
            int nn = (int)(ent >> 10);
            int kg = (int)(ent & 1023);
            float d2e = vq_rescore(rf, lds_sr[nn], sestg[kg], emb_s, nn, kg);
            unsigned long long pk =
                ((unsigned long long)__float_as_uint(d2e) << 32) | (unsigned)kg;
            atomicMin(&best64[nn], pk);
        }
        __syncthreads();                           // best64 final; queue dead

        // ---- finalize stage: idx/used; residual update ----
        if (tid < 64) {
            int bk = (int)(best64[tid] & 0xFFFFFFFFull) & (Kn - 1);
            bkL[tid] = bk;
            out_idx[s*Nn + n0 + tid] = (float)bk;
            used_g[s*Kn + bk] = 1.0f;
            best64[tid] = ~0ULL;                   // reset for next stage
        }
        if (tid == 0) qcnt[0] = 0;
        __syncthreads();                           // bkL visible

        const float* ep = emb_s + (size_t)bkL[nl]*Dn;
        if (s < NCB-1) {
            float nv[16];
            #pragma unroll
            for (int j = 0; j < 16; ++j) {
                int d = dg*16 + j;
                float rv = rf[d*64 + nl];
                float q  = ep[d];
                float diff = rv - q;               // loss uses raw q
                lsum = fmaf(diff, diff, lsum);
                float qst = rv + (q - rv);         // straight-through, fp32-faithful
                nv[j] = rv - qst;
                rf[d*64 + nl] = nv[j];
            }
            // sr partials of new residual
            float a0=0.f,a1=0.f,a2=0.f,a3=0.f;
            #pragma unroll
            for (int j = 0; j < 16; j += 4) {
                a0 = fmaf(nv[j+0], nv[j+0], a0);
                a1 = fmaf(nv[j+1], nv[j+1], a1);
                a2 = fmaf(nv[j+2], nv[j+2], a2);
                a3 = fmaf(nv[j+3], nv[j+3], a3);
            }
            srpart[dg*64 + nl] = (a0+a1)+(a2+a3);
            // bf16 split of new residual -> RH/RL
            unsigned short hi[16], lo[16];
            #pragma unroll
            for (int j = 0; j < 16; ++j) {
                hi[j] = f2bf(nv[j]);
                lo[j] = f2bf(nv[j] - bf2f(hi[j]));
            }
            s16x8 ph0, ph1, pl0, pl1;
            #pragma unroll
            for (int j = 0; j < 8; ++j) {
                ph0[j] = (short)hi[j];   ph1[j] = (short)hi[j+8];
                pl0[j] = (short)lo[j];   pl1[j] = (short)lo[j+8];
            }
            const int s0 = dg*2, s1 = dg*2 + 1, nx = nl & 7;
            *(s16x8*)(smem + SM_RH + nl*128 + ((s0 ^ nx) << 4)) = ph0;
            *(s16x8*)(smem + SM_RH + nl*128 + ((s1 ^ nx) << 4)) = ph1;
            *(s16x8*)(smem + SM_RL + nl*128 + ((s0 ^ nx) << 4)) = pl0;
            *(s16x8*)(smem + SM_RL + nl*128 + ((s1 ^ nx) << 4)) = pl1;
            __syncthreads();                       // srpart/rf/RH/RL writes done
            if (tid < 64)
                lds_sr[tid] = (srpart[tid] + srpart[64+tid])
                            + (srpart[128+tid] + srpart[192+tid]);
            *(float4*)&sestg[tid*4] = *(const float4*)&se_g[(s+1)*Kn + tid*4];
            __syncthreads();                       // lds_sr/sestg ready; srpart dead
        } else {
            // final stage: qt = x - res_final, written directly
            const int n = n0 + nl;
            const int b = n / Tn, t = n % Tn;
            const float* xp = x + b*(Dn*Tn) + t;
            float* qp = out_qt + b*(Dn*Tn) + t;
            #pragma unroll
            for (int j = 0; j < 16; ++j) {
                int d = dg*16 + j;
                float rv = rf[d*64 + nl];
                float q  = ep[d];
                float diff = rv - q;
                lsum = fmaf(diff, diff, lsum);
                float qst = rv + (q - rv);
                float rn = rv - qst;
                qp[d*Tn] = xp[d*Tn] - rn;
            }
        }
    }

    // ---- loss reduce (once for all 8 stages) ----
    float* red = (float*)(smem + SM_QUE);          // queue dead
    red[tid] = lsum;
    __syncthreads();
    for (int s2 = 128; s2 > 0; s2 >>= 1) {
        if (tid < s2) red[tid] += red[tid + s2];
        __syncthreads();
    }
    if (tid == 0) atomicAdd(loss_acc, red[0]);
}

// ---------- scalars: (commit+codebook)/NCB and utilization (fp32 out) ----------
__global__ void vq_scalars(const float* __restrict__ used, const float* __restrict__ loss_acc,
                           float* __restrict__ out)
{
    __shared__ float red[256];
    float s = 0.f;
    for (int j = threadIdx.x; j < NCB*Kn; j += 256) s += used[j];
    red[threadIdx.x] = s;
    __syncthreads();
    for (int st = 128; st > 0; st >>= 1) {
        if (threadIdx.x < st) red[threadIdx.x] += red[threadIdx.x + st];
        __syncthreads();
    }
    if (threadIdx.x == 0) {
        float sumsq = loss_acc[0];
        float total_loss = 2.0f * sumsq / (float)(Nn*Dn);  // sum over stages of commit+codebook
        out[OUT_SC_OFF + 0] = total_loss / (float)NCB;
        out[OUT_SC_OFF + 1] = red[0] / (float)(NCB*Kn);
    }
}

extern "C" void kernel_launch(void* const* d_in, const int* in_sizes, int n_in,
                              void* d_out, int out_size, void* d_ws, size_t ws_size,
                              hipStream_t stream)
{
    const float* x      = (const float*)d_in[0];
    const float* embeds = (const float*)d_in[1];
    float* out = (float*)d_out;
    char* ws = (char*)d_ws;

    char*  ehi   = ws + WS_EHI;
    float* se    = (float*)(ws + WS_SE);
    float* used  = (float*)(ws + WS_USED);
    float* loss  = (float*)(ws + WS_LOSS);
    float* semax = (float*)(ws + WS_SEMAX);

    // zero used + loss + semax (contiguous)
    hipMemsetAsync(used, 0, (size_t)NCB*Kn*sizeof(float) + 48, stream);

    vq_se<<<(NCB*Kn + 255)/256, 256, 0, stream>>>(embeds, se, semax);
    vq_ebf<<<256, 256, 0, stream>>>(embeds, ehi);

    vq_mega<<<NBLK, 256, 0, stream>>>(x, embeds, ehi, se, semax,
                                      out + OUT_QT_OFF, out + OUT_IDX_OFF,
                                      used, loss);

    vq_scalars<<<1, 256, 0, stream>>>(used, loss, out);
}